// Round 5
// baseline (2174.519 us; speedup 1.0000x reference)
//
#include <hip/hip_runtime.h>

// Problem shape (fixed by setup_inputs): B=4, N=16384, NPOINT=1024, nsample=1,
// radius=0.5. xyz input layout is [B,3,N]. Output: int32 [B,NPOINT,1].
//
// FPS: one block per batch (serial 1023-step loop; cross-block sync costs more
// than an iteration). 1024 threads = 16 waves = 4 waves/SIMD for latency
// hiding, 16 points/thread in registers.
//
// Diagnosis (rounds 0-3): iteration time is dominated by EXPOSED LATENCY, not
// issue count (round 0 vs 3: -100 insts -> +1% time). Biggest term: the
// 6-level u64 __shfl_xor butterfly = 12 ds_bpermute LDS round trips at
// ~120 cyc each, unhidden at 2 lockstep waves/SIMD. Fix: DPP max-reduce
// (row_shr 1/2/4/8 + row_bcast 15/31 — VALU-pipe lane swizzle, ~12 cyc/step)
// + 4 waves/SIMD to overlap the remaining LDS/SMEM/barrier tail.
// (Round 4 was an infra failure; resubmitted with far masked into range so a
// hypothetical reduce bug can only fail correctness, never fault the GPU.)
//
// Per iteration (ONE barrier):
//   scalar RN distance update + fused min/argmax (strict '>' with ascending k
//   == numpy first-occurrence) -> packed (value<<32 | 16383-idx) key ->
//   6-step DPP wave max (lands in lane 63) -> lane 63 writes LDS
//   (double-buffered) -> barrier -> all threads tree-max the 16 wave keys.
// Distance replicated exactly as numpy: ((dx*dx+dy*dy)+dz*dz), each op RN,
// no FMA contraction. Key packing: dist >= 0 so IEEE bits order == float
// order; low bits 16383-idx makes u64 max == (max val, tie -> min idx).

constexpr int N_PTS  = 16384;
constexpr int NPOINT = 1024;
constexpr int BLOCK  = 1024;           // 16 waves -> 4 waves/SIMD
constexpr int KPT    = N_PTS / BLOCK;  // 16 points/thread
constexpr int NWAVE  = BLOCK / 64;     // 16

__device__ inline unsigned long long pack_key(float v, int idx) {
    return ((unsigned long long)__float_as_uint(v) << 32) |
           (unsigned)(N_PTS - 1 - idx);
}
__device__ inline int key_idx(unsigned long long k) {
    return N_PTS - 1 - (int)(k & 0xFFFFu);
}
__device__ inline unsigned long long umax64(unsigned long long a,
                                            unsigned long long b) {
    return a > b ? a : b;
}

// One DPP max step on a u64 key: move both 32-bit halves with the same DPP
// control (so 'moved' is always one whole source lane's key), then u64-max
// with the unmoved key. bound_ctrl=false + old=self makes out-of-bounds /
// masked lanes a max-identity (they see their own value).
template <int CTRL, int RM, int BM>
__device__ inline unsigned long long dpp_max_step(unsigned long long key) {
    const int lo = (int)(unsigned)key;
    const int hi = (int)(unsigned)(key >> 32);
    const unsigned mlo =
        (unsigned)__builtin_amdgcn_update_dpp(lo, lo, CTRL, RM, BM, false);
    const unsigned mhi =
        (unsigned)__builtin_amdgcn_update_dpp(hi, hi, CTRL, RM, BM, false);
    const unsigned long long moved = ((unsigned long long)mhi << 32) | mlo;
    return key > moved ? key : moved;
}

// Full 64-lane max reduction; result valid in lane 63.
__device__ inline unsigned long long wave_max_key(unsigned long long key) {
    key = dpp_max_step<0x111, 0xf, 0xf>(key);  // row_shr:1
    key = dpp_max_step<0x112, 0xf, 0xf>(key);  // row_shr:2
    key = dpp_max_step<0x114, 0xf, 0xe>(key);  // row_shr:4
    key = dpp_max_step<0x118, 0xf, 0xc>(key);  // row_shr:8
    key = dpp_max_step<0x142, 0xa, 0xf>(key);  // row_bcast:15
    key = dpp_max_step<0x143, 0xc, 0xf>(key);  // row_bcast:31
    return key;
}

__global__ __launch_bounds__(BLOCK, 4) void fps_kernel(
    const float* __restrict__ xyz,   // [B,3,N]
    int* __restrict__ cent)          // [B,NPOINT] workspace
{
    const int b   = blockIdx.x;
    const int tid = threadIdx.x;
    const float* X = xyz + (size_t)b * 3 * N_PTS;
    const float* Y = X + N_PTS;
    const float* Z = X + 2 * N_PTS;

    float px[KPT], py[KPT], pz[KPT], dst[KPT];
#pragma unroll
    for (int k = 0; k < KPT; ++k) {
        const int p = tid + k * BLOCK;   // strided: coalesced, ascending/thread
        px[k] = X[p];
        py[k] = Y[p];
        pz[k] = Z[p];
        dst[k] = 1e10f;                  // BIG
    }

    __shared__ unsigned long long s_key[2][NWAVE];  // double-buffered

    const int wave = tid >> 6;
    const int lane = tid & 63;

    // ---- initial far: argmax over x (first occurrence: ascending, strict >)
    int far;
    {
        float bv = px[0];
        int   bi = tid;
#pragma unroll
        for (int k = 1; k < KPT; ++k) {
            if (px[k] > bv) { bv = px[k]; bi = tid + k * BLOCK; }
        }
        const unsigned long long key = wave_max_key(pack_key(bv, bi));
        if (lane == 63) s_key[0][wave] = key;
        __syncthreads();
        const unsigned long long* sk = s_key[0];
        unsigned long long m0 = umax64(umax64(sk[0], sk[1]),
                                       umax64(sk[2], sk[3]));
        unsigned long long m1 = umax64(umax64(sk[4], sk[5]),
                                       umax64(sk[6], sk[7]));
        unsigned long long m2 = umax64(umax64(sk[8], sk[9]),
                                       umax64(sk[10], sk[11]));
        unsigned long long m3 = umax64(umax64(sk[12], sk[13]),
                                       umax64(sk[14], sk[15]));
        far = __builtin_amdgcn_readfirstlane(
                  key_idx(umax64(umax64(m0, m1), umax64(m2, m3)))) &
              (N_PTS - 1);               // fault guard: always in-bounds
    }

    // ---- main FPS loop: one barrier per iteration ----
    for (int it = 0; it < NPOINT; ++it) {
        if (tid == 0) cent[b * NPOINT + it] = far;   // record PRE-update far
        if (it == NPOINT - 1) break;                 // last update is unused

        // centroid coords: far is uniform (SGPR) -> scalar broadcast loads
        const float cx = X[far];
        const float cy = Y[far];
        const float cz = Z[far];

        float nbv = -1.0f;
        int   nbi = 0;
#pragma unroll
        for (int k = 0; k < KPT; ++k) {
            const float dx = __fsub_rn(px[k], cx);
            const float dy = __fsub_rn(py[k], cy);
            const float dz = __fsub_rn(pz[k], cz);
            const float d  = __fadd_rn(
                __fadd_rn(__fmul_rn(dx, dx), __fmul_rn(dy, dy)),
                __fmul_rn(dz, dz));
            const float nd = fminf(dst[k], d);
            dst[k] = nd;
            if (nd > nbv) { nbv = nd; nbi = tid + k * BLOCK; }
        }

        const unsigned long long key = wave_max_key(pack_key(nbv, nbi));
        const int buf = (it + 1) & 1;
        if (lane == 63) s_key[buf][wave] = key;
        __syncthreads();

        const unsigned long long* sk = s_key[buf];
        unsigned long long m0 = umax64(umax64(sk[0], sk[1]),
                                       umax64(sk[2], sk[3]));
        unsigned long long m1 = umax64(umax64(sk[4], sk[5]),
                                       umax64(sk[6], sk[7]));
        unsigned long long m2 = umax64(umax64(sk[8], sk[9]),
                                       umax64(sk[10], sk[11]));
        unsigned long long m3 = umax64(umax64(sk[12], sk[13]),
                                       umax64(sk[14], sk[15]));
        far = __builtin_amdgcn_readfirstlane(
                  key_idx(umax64(umax64(m0, m1), umax64(m2, m3)))) &
              (N_PTS - 1);               // fault guard
    }
}

// ---------------------------------------------------------------------------
// Ball query, nsample=1: one wave per centroid; scan 64-point chunks from
// index 0, first hit wins (== min index within radius). Distance replicated
// as the reference einsum: ((-2*dot) + |c|^2) + |p|^2; keep-test d <= 0.25.
// ---------------------------------------------------------------------------
__global__ __launch_bounds__(256) void ballq_kernel(
    const float* __restrict__ xyz,   // [B,3,N]
    const int* __restrict__ cent,    // [B,NPOINT]
    int* __restrict__ out)           // [B,NPOINT]
{
    const int gw   = (blockIdx.x * 256 + threadIdx.x) >> 6; // global wave id
    const int lane = threadIdx.x & 63;
    const int b = gw / NPOINT;
    const int s = gw % NPOINT;

    const float* X = xyz + (size_t)b * 3 * N_PTS;
    const float* Y = X + N_PTS;
    const float* Z = X + 2 * N_PTS;

    const int ci = cent[b * NPOINT + s] & (N_PTS - 1);  // fault guard
    const float cx = X[ci];
    const float cy = Y[ci];
    const float cz = Z[ci];
    const float cn = __fadd_rn(
        __fadd_rn(__fmul_rn(cx, cx), __fmul_rn(cy, cy)), __fmul_rn(cz, cz));

    int res = N_PTS;
    for (int base = 0; base < N_PTS; base += 64) {
        const int p = base + lane;
        const float x = X[p];
        const float y = Y[p];
        const float z = Z[p];
        const float dot = __fadd_rn(
            __fadd_rn(__fmul_rn(x, cx), __fmul_rn(y, cy)), __fmul_rn(z, cz));
        const float pn = __fadd_rn(
            __fadd_rn(__fmul_rn(x, x), __fmul_rn(y, y)), __fmul_rn(z, z));
        const float d = __fadd_rn(__fadd_rn(__fmul_rn(-2.0f, dot), cn), pn);
        const bool hit = !(d > 0.25f);
        const unsigned long long m = __ballot(hit);
        if (m) {                       // wave-uniform branch
            res = base + (__ffsll((long long)m) - 1);
            break;
        }
    }
    if (lane == 0) out[b * NPOINT + s] = res;
}

extern "C" void kernel_launch(void* const* d_in, const int* in_sizes, int n_in,
                              void* d_out, int out_size, void* d_ws, size_t ws_size,
                              hipStream_t stream) {
    const float* xyz = (const float*)d_in[0];
    const int B = in_sizes[1] / 16;          // cls_label is [B,16]
    int* cent = (int*)d_ws;                  // [B, NPOINT] scratch
    int* out  = (int*)d_out;                 // int32 [B, NPOINT, 1]

    fps_kernel<<<B, BLOCK, 0, stream>>>(xyz, cent);

    const int nwaves  = B * NPOINT;          // one wave per centroid
    const int nblocks = nwaves / 4;          // 256 threads = 4 waves/block
    ballq_kernel<<<nblocks, 256, 0, stream>>>(xyz, cent, out);
}

// Round 6
// 1729.807 us; speedup vs baseline: 1.2571x; 1.2571x over previous
//
#include <hip/hip_runtime.h>

// Problem shape (fixed by setup_inputs): B=4, N=16384, NPOINT=1024, nsample=1,
// radius=0.5. xyz input layout is [B,3,N]. Output: int32 [B,NPOINT,1].
//
// FPS: one block per batch (serial 1023-step loop). 512 threads = 8 waves =
// 2 waves/SIMD, 32 points/thread.
//
// Unified diagnosis of rounds 0-5: in every version VGPR_Count << live state
// (96 vs ~150, 52 vs ~84) -> the register allocator REMATERIALIZES the
// coordinate loads every iteration (plus their VALU address calc) instead of
// keeping them resident. That remat traffic dominates; thread-count and
// reduce-style changes only shuffled it around (1024t made it worse: 52 regs;
// DPP's saving was swamped). The round-3 asm pin failed because non-volatile
// asm with register outputs is itself rematerializable.
//
// Fixes in this round:
//  * amdgpu_waves_per_eu(2,2): max occupancy 2 waves/EU -> allocator has no
//    incentive to target < 256 VGPRs.
//  * asm VOLATILE pin of px/py/pz after load: cannot be cloned or remat'd.
//  * DPP wave-max (row_shr 1/2/4/8 + row_bcast 15/31 — HW-verified correct in
//    round 5): VALU-pipe lane swizzle replaces 12 ds_bpermute LDS round trips.
//
// Per iteration (ONE barrier):
//   scalar RN distance update + fused min/argmax (strict '>' with ascending k
//   == numpy first-occurrence) -> packed (value<<32 | 16383-idx) key ->
//   6-step DPP wave max (lands in lane 63) -> lane 63 writes LDS
//   (double-buffered) -> barrier -> all threads tree-max the 8 wave keys.
// Distance replicated exactly as numpy: ((dx*dx+dy*dy)+dz*dz), each op RN,
// no FMA contraction. Key packing: dist >= 0 so IEEE bits order == float
// order; low bits 16383-idx makes u64 max == (max val, tie -> min idx).

constexpr int N_PTS  = 16384;
constexpr int NPOINT = 1024;
constexpr int BLOCK  = 512;            // 8 waves -> 2 waves/SIMD
constexpr int KPT    = N_PTS / BLOCK;  // 32 points/thread
constexpr int NWAVE  = BLOCK / 64;     // 8

__device__ inline unsigned long long pack_key(float v, int idx) {
    return ((unsigned long long)__float_as_uint(v) << 32) |
           (unsigned)(N_PTS - 1 - idx);
}
__device__ inline int key_idx(unsigned long long k) {
    return N_PTS - 1 - (int)(k & 0xFFFFu);
}
__device__ inline unsigned long long umax64(unsigned long long a,
                                            unsigned long long b) {
    return a > b ? a : b;
}

// One DPP max step on a u64 key: move both 32-bit halves with the same DPP
// control (so 'moved' is always one whole source lane's key), then u64-max
// with the unmoved key. bound_ctrl=false + old=self makes out-of-bounds /
// masked lanes a max-identity (they see their own value).
template <int CTRL, int RM, int BM>
__device__ inline unsigned long long dpp_max_step(unsigned long long key) {
    const int lo = (int)(unsigned)key;
    const int hi = (int)(unsigned)(key >> 32);
    const unsigned mlo =
        (unsigned)__builtin_amdgcn_update_dpp(lo, lo, CTRL, RM, BM, false);
    const unsigned mhi =
        (unsigned)__builtin_amdgcn_update_dpp(hi, hi, CTRL, RM, BM, false);
    const unsigned long long moved = ((unsigned long long)mhi << 32) | mlo;
    return key > moved ? key : moved;
}

// Full 64-lane max reduction (canonical gfx9 wave64 pattern; HW-verified
// round 5). Result valid in lane 63.
__device__ inline unsigned long long wave_max_key(unsigned long long key) {
    key = dpp_max_step<0x111, 0xf, 0xf>(key);  // row_shr:1
    key = dpp_max_step<0x112, 0xf, 0xf>(key);  // row_shr:2
    key = dpp_max_step<0x114, 0xf, 0xe>(key);  // row_shr:4
    key = dpp_max_step<0x118, 0xf, 0xc>(key);  // row_shr:8
    key = dpp_max_step<0x142, 0xa, 0xf>(key);  // row_bcast:15
    key = dpp_max_step<0x143, 0xc, 0xf>(key);  // row_bcast:31
    return key;
}

__global__ __launch_bounds__(BLOCK)
__attribute__((amdgpu_waves_per_eu(2, 2))) void fps_kernel(
    const float* __restrict__ xyz,   // [B,3,N]
    int* __restrict__ cent)          // [B,NPOINT] workspace
{
    const int b   = blockIdx.x;
    const int tid = threadIdx.x;
    const float* X = xyz + (size_t)b * 3 * N_PTS;
    const float* Y = X + N_PTS;
    const float* Z = X + 2 * N_PTS;

    float px[KPT], py[KPT], pz[KPT], dst[KPT];
#pragma unroll
    for (int k = 0; k < KPT; ++k) {
        const int p = tid + k * BLOCK;   // strided: coalesced, ascending/thread
        px[k] = X[p];
        py[k] = Y[p];
        pz[k] = Z[p];
        dst[k] = 1e10f;                  // BIG
    }
    // Pin the point cloud in VGPRs. VOLATILE: the asm cannot be cloned,
    // sunk, or rematerialized, so the 96 coord values stay register-resident
    // for the whole kernel (budget 256 via waves_per_eu(2,2)).
#pragma unroll
    for (int k = 0; k < KPT; ++k)
        asm volatile("" : "+v"(px[k]), "+v"(py[k]), "+v"(pz[k]));

    __shared__ unsigned long long s_key[2][NWAVE];  // double-buffered

    const int wave = tid >> 6;
    const int lane = tid & 63;

    // ---- initial far: argmax over x (first occurrence: ascending, strict >)
    int far;
    {
        float bv = px[0];
        int   bi = tid;
#pragma unroll
        for (int k = 1; k < KPT; ++k) {
            if (px[k] > bv) { bv = px[k]; bi = tid + k * BLOCK; }
        }
        const unsigned long long key = wave_max_key(pack_key(bv, bi));
        if (lane == 63) s_key[0][wave] = key;
        __syncthreads();
        const unsigned long long* sk = s_key[0];
        const unsigned long long bkk =
            umax64(umax64(umax64(sk[0], sk[1]), umax64(sk[2], sk[3])),
                   umax64(umax64(sk[4], sk[5]), umax64(sk[6], sk[7])));
        far = __builtin_amdgcn_readfirstlane(key_idx(bkk)) &
              (N_PTS - 1);               // fault guard: always in-bounds
    }

    // ---- main FPS loop: one barrier per iteration ----
    for (int it = 0; it < NPOINT; ++it) {
        if (tid == 0) cent[b * NPOINT + it] = far;   // record PRE-update far
        if (it == NPOINT - 1) break;                 // last update is unused

        // centroid coords: far is uniform (SGPR) -> scalar broadcast loads
        const float cx = X[far];
        const float cy = Y[far];
        const float cz = Z[far];

        float nbv = -1.0f;
        int   nbi = 0;
#pragma unroll
        for (int k = 0; k < KPT; ++k) {
            const float dx = __fsub_rn(px[k], cx);
            const float dy = __fsub_rn(py[k], cy);
            const float dz = __fsub_rn(pz[k], cz);
            const float d  = __fadd_rn(
                __fadd_rn(__fmul_rn(dx, dx), __fmul_rn(dy, dy)),
                __fmul_rn(dz, dz));
            const float nd = fminf(dst[k], d);
            dst[k] = nd;
            if (nd > nbv) { nbv = nd; nbi = tid + k * BLOCK; }
        }

        const unsigned long long key = wave_max_key(pack_key(nbv, nbi));
        const int buf = (it + 1) & 1;
        if (lane == 63) s_key[buf][wave] = key;
        __syncthreads();

        const unsigned long long* sk = s_key[buf];
        const unsigned long long bkk =
            umax64(umax64(umax64(sk[0], sk[1]), umax64(sk[2], sk[3])),
                   umax64(umax64(sk[4], sk[5]), umax64(sk[6], sk[7])));
        far = __builtin_amdgcn_readfirstlane(key_idx(bkk)) &
              (N_PTS - 1);               // fault guard
    }
}

// ---------------------------------------------------------------------------
// Ball query, nsample=1: one wave per centroid; scan 64-point chunks from
// index 0, first hit wins (== min index within radius). Distance replicated
// as the reference einsum: ((-2*dot) + |c|^2) + |p|^2; keep-test d <= 0.25.
// ---------------------------------------------------------------------------
__global__ __launch_bounds__(256) void ballq_kernel(
    const float* __restrict__ xyz,   // [B,3,N]
    const int* __restrict__ cent,    // [B,NPOINT]
    int* __restrict__ out)           // [B,NPOINT]
{
    const int gw   = (blockIdx.x * 256 + threadIdx.x) >> 6; // global wave id
    const int lane = threadIdx.x & 63;
    const int b = gw / NPOINT;
    const int s = gw % NPOINT;

    const float* X = xyz + (size_t)b * 3 * N_PTS;
    const float* Y = X + N_PTS;
    const float* Z = X + 2 * N_PTS;

    const int ci = cent[b * NPOINT + s] & (N_PTS - 1);  // fault guard
    const float cx = X[ci];
    const float cy = Y[ci];
    const float cz = Z[ci];
    const float cn = __fadd_rn(
        __fadd_rn(__fmul_rn(cx, cx), __fmul_rn(cy, cy)), __fmul_rn(cz, cz));

    int res = N_PTS;
    for (int base = 0; base < N_PTS; base += 64) {
        const int p = base + lane;
        const float x = X[p];
        const float y = Y[p];
        const float z = Z[p];
        const float dot = __fadd_rn(
            __fadd_rn(__fmul_rn(x, cx), __fmul_rn(y, cy)), __fmul_rn(z, cz));
        const float pn = __fadd_rn(
            __fadd_rn(__fmul_rn(x, x), __fmul_rn(y, y)), __fmul_rn(z, z));
        const float d = __fadd_rn(__fadd_rn(__fmul_rn(-2.0f, dot), cn), pn);
        const bool hit = !(d > 0.25f);
        const unsigned long long m = __ballot(hit);
        if (m) {                       // wave-uniform branch
            res = base + (__ffsll((long long)m) - 1);
            break;
        }
    }
    if (lane == 0) out[b * NPOINT + s] = res;
}

extern "C" void kernel_launch(void* const* d_in, const int* in_sizes, int n_in,
                              void* d_out, int out_size, void* d_ws, size_t ws_size,
                              hipStream_t stream) {
    const float* xyz = (const float*)d_in[0];
    const int B = in_sizes[1] / 16;          // cls_label is [B,16]
    int* cent = (int*)d_ws;                  // [B, NPOINT] scratch
    int* out  = (int*)d_out;                 // int32 [B, NPOINT, 1]

    fps_kernel<<<B, BLOCK, 0, stream>>>(xyz, cent);

    const int nwaves  = B * NPOINT;          // one wave per centroid
    const int nblocks = nwaves / 4;          // 256 threads = 4 waves/block
    ballq_kernel<<<nblocks, 256, 0, stream>>>(xyz, cent, out);
}